// Round 2
// baseline (719.501 us; speedup 1.0000x reference)
//
#include <hip/hip_runtime.h>
#include <hip/hip_bf16.h>

#define B_ROWS 16384
#define KDIM   2048   // D + H
#define NDIM   5120   // 5*H
#define HDIM   1024

// ---- 256x256 deep-pipelined GEMM geometry ----
#define BM 256
#define BN 256
#define BK 32
#define NK (KDIM / BK)            // 64 K-tiles
#define BUFSZ 32768               // one buffer: A 16KB + B 16KB
#define NBUF  4
#define LDS_BYTES (NBUF * BUFSZ)  // 131072 (dynamic LDS, opt-in)

typedef __attribute__((ext_vector_type(8))) short short8;
typedef __attribute__((ext_vector_type(4))) float f32x4;

__device__ __forceinline__ void async_cp16(const void* g, void* l) {
  __builtin_amdgcn_global_load_lds(
      (const __attribute__((address_space(1))) void*)g,
      (__attribute__((address_space(3))) void*)l,
      16, 0, 0);
}

// ---------------------------------------------------------------------------
// dtype probe: x is N(0,1). If stored bf16, no 16-bit word has exponent
// field >= 137 (|v| >= 2^10). If stored fp32, half the words are uniform
// mantissa noise -> ~46% exceed it. flag=1 -> fp32 inputs, flag=0 -> bf16.
// ---------------------------------------------------------------------------
__global__ void detect_dtype(const unsigned short* __restrict__ p, int* flag) {
  __shared__ int cnt;
  if (threadIdx.x == 0) cnt = 0;
  __syncthreads();
  int h = 0;
  for (int i = threadIdx.x; i < 2048; i += 256) {
    int e = (p[i] >> 7) & 0xFF;
    if (e >= 137) h++;
  }
  atomicAdd(&cnt, h);
  __syncthreads();
  if (threadIdx.x == 0) *flag = (cnt >= 4) ? 1 : 0;
}

// ---------------------------------------------------------------------------
// pack rows [rbase, rbase+rows) of fp32 (s0|s1) -> bf16 [rows,2048].
// No-op when inputs are already bf16 (flag==0).
// ---------------------------------------------------------------------------
__global__ void pack_pair_f32(const float* __restrict__ s0, const float* __restrict__ s1,
                              __hip_bfloat16* __restrict__ dst, const int* __restrict__ flag,
                              long rbase, long total) {
  if (*flag == 0) return;
  long idx = ((long)blockIdx.x * blockDim.x + threadIdx.x) * 8;
  if (idx >= total) return;
  int  k = (int)(idx & (KDIM - 1));
  long r = (idx >> 11) + rbase;
  const float* s = (k < 1024) ? (s0 + r * 1024 + k) : (s1 + r * 1024 + (k - 1024));
  float4 v0 = ((const float4*)s)[0];
  float4 v1 = ((const float4*)s)[1];
  union { short8 v; __hip_bfloat16 e[8]; } u;
  u.e[0] = __float2bfloat16(v0.x); u.e[1] = __float2bfloat16(v0.y);
  u.e[2] = __float2bfloat16(v0.z); u.e[3] = __float2bfloat16(v0.w);
  u.e[4] = __float2bfloat16(v1.x); u.e[5] = __float2bfloat16(v1.y);
  u.e[6] = __float2bfloat16(v1.z); u.e[7] = __float2bfloat16(v1.w);
  *(short8*)(dst + idx) = u.v;
}

// ---------------------------------------------------------------------------
// 256x256 counted-vmcnt pipelined bf16 GEMM for one row-chunk (rows>=4096):
//   G[rows,5120] = A[rows,2048] @ W[5120,2048]^T
// 8 waves (2M x 4N), BK=32, 4 LDS buffers, prefetch depth 3 (vmcnt(12)).
// T2 XOR-swizzle: LDS slot (row, sc) holds data chunk sc ^ ((row>>1)&3);
// global source is pre-swizzled per lane (both-sides involution, rule #21).
// flag=1: A/W from packed ws buffers. flag=0: stage directly from bf16
// inputs x|h_prev and Wx|Uh (BK=32 tiles never straddle k=1024).
// ---------------------------------------------------------------------------
__global__ __launch_bounds__(512, 2) void gemm_bt256(
    const __hip_bfloat16* __restrict__ Abf, const __hip_bfloat16* __restrict__ Wbf,
    const void* __restrict__ xr, const void* __restrict__ hr,
    const void* __restrict__ Wxr, const void* __restrict__ Uhr,
    __hip_bfloat16* __restrict__ G, const int* __restrict__ flag, int row_base) {
  extern __shared__ char lds[];

  const int tid = threadIdx.x;
  const int w   = tid >> 6;     // wave 0..7
  const int l   = tid & 63;

  const int m0l = blockIdx.y * BM;   // chunk-local tile row base
  const int n0  = blockIdx.x * BN;

  const int wm = w >> 2;   // 0..1 -> out rows wm*128..+128
  const int wn = w & 3;    // 0..3 -> out cols wn*64..+64

  // ---- staging setup: instr i of wave w fills LDS slots w*128 + i*64 + lane
  // (16B chunks). slot row = slot>>2; slot sc = slot&3 holds data chunk
  // dc = sc ^ ((row>>1)&3). Per-lane pre-swizzled global source:
  const int fl = *flag;
  const __hip_bfloat16* pA[2];
  const __hip_bfloat16* pW[2];
  long dA, dW;  // element delta from k<1024 source to k>=1024 source
  {
    const int r0 = w * 32 + (l >> 2);
#pragma unroll
    for (int i = 0; i < 2; ++i) {
      const int sr = r0 + i * 16;                 // tile-local staged row
      const int dc = (l & 3) ^ ((sr >> 1) & 3);   // data chunk at this slot
      if (fl) {
        pA[i] = Abf + (long)(m0l + sr) * KDIM + dc * 8;
        pW[i] = Wbf + (long)(n0 + sr) * KDIM + dc * 8;
      } else {
        pA[i] = (const __hip_bfloat16*)xr  + (long)(row_base + m0l + sr) * 1024 + dc * 8;
        pW[i] = (const __hip_bfloat16*)Wxr + (long)(n0 + sr) * 1024 + dc * 8;
      }
    }
    if (fl) { dA = 1024; dW = 1024; }
    else {
      dA = (const __hip_bfloat16*)hr  - (const __hip_bfloat16*)xr;
      dW = (const __hip_bfloat16*)Uhr - (const __hip_bfloat16*)Wxr;
    }
  }

#define STAGE(T) do {                                                        \
    const int  b_  = (T) & 3;                                                \
    const int  k0_ = (T) * BK;                                               \
    const long ko_ = (k0_ < 1024) ? (long)k0_ : (dA + (k0_ - 1024));         \
    const long kw_ = (k0_ < 1024) ? (long)k0_ : (dW + (k0_ - 1024));         \
    char* la_ = lds + b_ * BUFSZ + w * 2048;                                 \
    char* lw_ = la_ + 16384;                                                 \
    _Pragma("unroll")                                                        \
    for (int i_ = 0; i_ < 2; ++i_) {                                         \
      async_cp16(pA[i_] + ko_, la_ + i_ * 1024);                             \
      async_cp16(pW[i_] + kw_, lw_ + i_ * 1024);                             \
    }                                                                        \
  } while (0)

  f32x4 acc[8][4] = {};
  const int frow  = l & 15;
  const int swz   = (((l >> 4) ^ ((frow >> 1) & 3)) << 4);  // per-lane const
  const int arow0 = wm * 128 + frow;
  const int brow0 = wn * 64 + frow;

#define COMPUTE(T) do {                                                      \
    const char* ba_ = lds + ((T) & 3) * BUFSZ;                               \
    const char* bw_ = ba_ + 16384;                                           \
    short8 af_[8], wf_[4];                                                   \
    _Pragma("unroll")                                                        \
    for (int mi = 0; mi < 8; ++mi)                                           \
      af_[mi] = *(const short8*)(ba_ + (arow0 + mi * 16) * 64 + swz);        \
    _Pragma("unroll")                                                        \
    for (int ni = 0; ni < 4; ++ni)                                           \
      wf_[ni] = *(const short8*)(bw_ + (brow0 + ni * 16) * 64 + swz);        \
    __builtin_amdgcn_s_setprio(1);                                           \
    _Pragma("unroll")                                                        \
    for (int mi = 0; mi < 8; ++mi)                                           \
      _Pragma("unroll")                                                      \
      for (int ni = 0; ni < 4; ++ni)                                         \
        acc[mi][ni] = __builtin_amdgcn_mfma_f32_16x16x32_bf16(               \
            af_[mi], wf_[ni], acc[mi][ni], 0, 0, 0);                         \
    __builtin_amdgcn_s_setprio(0);                                           \
  } while (0)

  STAGE(0); STAGE(1); STAGE(2);

  int t = 0;
  // main loop: counted vmcnt -- 3 tiles (12 loads) stay in flight, never 0
  for (; t < NK - 3; ++t) {
    __builtin_amdgcn_s_barrier();            // all waves done reading buf[(t+3)&3]
    __builtin_amdgcn_sched_barrier(0);
    STAGE(t + 3);
    asm volatile("s_waitcnt vmcnt(12)" ::: "memory");  // tile t landed
    __builtin_amdgcn_s_barrier();            // tile t visible to all waves
    __builtin_amdgcn_sched_barrier(0);
    COMPUTE(t);
  }
  // tail: no more stages; drain
  for (; t < NK; ++t) {
    __builtin_amdgcn_s_barrier();
    __builtin_amdgcn_sched_barrier(0);
    asm volatile("s_waitcnt vmcnt(0)" ::: "memory");
    __builtin_amdgcn_s_barrier();
    __builtin_amdgcn_sched_barrier(0);
    COMPUTE(t);
  }

#undef STAGE
#undef COMPUTE

  // C/D layout (m89-verified): col = lane&15, row = (lane>>4)*4 + reg
  const int c_col = l & 15;
  const int c_row = (l >> 4) * 4;
#pragma unroll
  for (int mi = 0; mi < 8; ++mi) {
#pragma unroll
    for (int r = 0; r < 4; ++r) {
      long m = (long)(m0l + wm * 128 + mi * 16 + c_row + r);
      __hip_bfloat16* gp = G + m * NDIM + n0 + wn * 64 + c_col;
#pragma unroll
      for (int ni = 0; ni < 4; ++ni)
        gp[ni * 16] = __float2bfloat16(acc[mi][ni][r]);
    }
  }
}

// ---------------------------------------------------------------------------
// proven m97-structure 128x128 GEMM (harness-verified @749.8us) — fallback
// for small row-chunks where the 256-tile grid would underfill the CUs.
// ---------------------------------------------------------------------------
__global__ __launch_bounds__(256, 2) void gemm_bt128(
    const __hip_bfloat16* __restrict__ Abf, const __hip_bfloat16* __restrict__ Wbf,
    const void* __restrict__ xr, const void* __restrict__ hr,
    const void* __restrict__ Wxr, const void* __restrict__ Uhr,
    __hip_bfloat16* __restrict__ G, const int* __restrict__ flag, int row_base) {
  __shared__ __hip_bfloat16 As[128 * 64];
  __shared__ __hip_bfloat16 Ws[128 * 64];

  const int tid  = threadIdx.x;
  const int wave = tid >> 6;
  const int lane = tid & 63;

  const int m0l = blockIdx.y * 128;
  const int n0  = blockIdx.x * 128;

  const int wm = (wave >> 1) * 64;
  const int wn = (wave & 1) * 64;

  const int srl  = m0l + wave * 32 + (lane >> 3);
  const int srw  = n0  + wave * 32 + (lane >> 3);
  const int scol = (lane & 7) * 8;

  const int fl = *flag;
  const __hip_bfloat16 *pA0, *pA1, *pW0, *pW1;
  long rsA, rsW;
  if (fl) {
    pA0 = Abf + (long)srl * KDIM + scol; pA1 = pA0 + 1024; rsA = KDIM;
    pW0 = Wbf + (long)srw * KDIM + scol; pW1 = pW0 + 1024; rsW = KDIM;
  } else {
    pA0 = (const __hip_bfloat16*)xr  + (long)(row_base + srl) * 1024 + scol;
    pA1 = (const __hip_bfloat16*)hr  + (long)(row_base + srl) * 1024 + scol;
    pW0 = (const __hip_bfloat16*)Wxr + (long)srw * 1024 + scol;
    pW1 = (const __hip_bfloat16*)Uhr + (long)srw * 1024 + scol;
    rsA = 1024; rsW = 1024;
  }

  __hip_bfloat16* a_l = As + (wave * 32) * 64;
  __hip_bfloat16* w_l = Ws + (wave * 32) * 64;

  f32x4 acc[4][4] = {};
  const int frow = lane & 15;
  const int fk   = (lane >> 4) * 8;

  for (int k0 = 0; k0 < KDIM; k0 += 64) {
    const __hip_bfloat16* ag = (k0 < 1024) ? pA0 + k0 : pA1 + (k0 - 1024);
    const __hip_bfloat16* wg = (k0 < 1024) ? pW0 + k0 : pW1 + (k0 - 1024);
    __syncthreads();
#pragma unroll
    for (int i = 0; i < 4; ++i) {
      async_cp16(ag + (long)i * 8 * rsA, a_l + i * 8 * 64);
      async_cp16(wg + (long)i * 8 * rsW, w_l + i * 8 * 64);
    }
    __syncthreads();
#pragma unroll
    for (int kk = 0; kk < 64; kk += 32) {
      short8 af[4], wf[4];
#pragma unroll
      for (int mi = 0; mi < 4; ++mi)
        af[mi] = *(const short8*)(As + (wm + mi * 16 + frow) * 64 + kk + fk);
#pragma unroll
      for (int ni = 0; ni < 4; ++ni)
        wf[ni] = *(const short8*)(Ws + (wn + ni * 16 + frow) * 64 + kk + fk);
#pragma unroll
      for (int mi = 0; mi < 4; ++mi)
#pragma unroll
        for (int ni = 0; ni < 4; ++ni)
          acc[mi][ni] = __builtin_amdgcn_mfma_f32_16x16x32_bf16(
              af[mi], wf[ni], acc[mi][ni], 0, 0, 0);
    }
  }

  const int c_col = lane & 15;
  const int c_row = (lane >> 4) * 4;
#pragma unroll
  for (int mi = 0; mi < 4; ++mi) {
#pragma unroll
    for (int r = 0; r < 4; ++r) {
      long m = (long)(m0l + wm + mi * 16 + c_row + r);
      __hip_bfloat16* gp = G + m * NDIM + n0 + wn + c_col;
#pragma unroll
      for (int ni = 0; ni < 4; ++ni)
        gp[ni * 16] = __float2bfloat16(acc[mi][ni][r]);
    }
  }
}

// ---------------------------------------------------------------------------
// elementwise LSTM update for one row-chunk. Output ALWAYS fp32:
// out = [h_t (B*H) | c_t (B*H)]. c_prev/dw/biases read per flag dtype.
// ---------------------------------------------------------------------------
__global__ void lstm_ep(const __hip_bfloat16* __restrict__ G,
                        const void* __restrict__ cpr, const void* __restrict__ dwr,
                        const void* __restrict__ bxr, const void* __restrict__ bhr,
                        float* __restrict__ out, const int* __restrict__ flag,
                        long row_base, long rows) {
  const long t = ((long)blockIdx.x * blockDim.x + threadIdx.x) * 8;
  if (t >= rows * HDIM) return;
  const long bl = t >> 10;            // chunk-local row
  const int  h  = (int)(t & 1023);
  const long ig = (row_base + bl) * HDIM + h;  // global element index

  const int fl = *flag;
  const __hip_bfloat16* g = G + bl * (long)NDIM + h;

  union S8 { short8 v; __hip_bfloat16 e[8]; };
  union F8 { float4 v[2]; float f[8]; };

  S8 vg[5];
  F8 bias[5];
#pragma unroll
  for (int q = 0; q < 5; ++q) {
    vg[q].v = *(const short8*)(g + q * 1024);
    if (fl) {
      bias[q].v[0] = *(const float4*)((const float*)bxr + q * 1024 + h);
      bias[q].v[1] = *(const float4*)((const float*)bxr + q * 1024 + h + 4);
      F8 b2;
      b2.v[0] = *(const float4*)((const float*)bhr + q * 1024 + h);
      b2.v[1] = *(const float4*)((const float*)bhr + q * 1024 + h + 4);
#pragma unroll
      for (int j = 0; j < 8; ++j) bias[q].f[j] += b2.f[j];
    } else {
      S8 b1, b2;
      b1.v = *(const short8*)((const __hip_bfloat16*)bxr + q * 1024 + h);
      b2.v = *(const short8*)((const __hip_bfloat16*)bhr + q * 1024 + h);
#pragma unroll
      for (int j = 0; j < 8; ++j)
        bias[q].f[j] = __bfloat162float(b1.e[j]) + __bfloat162float(b2.e[j]);
    }
  }

  F8 cp, dv;
  if (fl) {
    cp.v[0] = *(const float4*)((const float*)cpr + ig);
    cp.v[1] = *(const float4*)((const float*)cpr + ig + 4);
    dv.v[0] = *(const float4*)((const float*)dwr + ig);
    dv.v[1] = *(const float4*)((const float*)dwr + ig + 4);
  } else {
    S8 c8, d8;
    c8.v = *(const short8*)((const __hip_bfloat16*)cpr + ig);
    d8.v = *(const short8*)((const __hip_bfloat16*)dwr + ig);
#pragma unroll
    for (int j = 0; j < 8; ++j) {
      cp.f[j] = __bfloat162float(c8.e[j]);
      dv.f[j] = __bfloat162float(d8.e[j]);
    }
  }

  F8 oh, oc;
#pragma unroll
  for (int j = 0; j < 8; ++j) {
    float gi = __bfloat162float(vg[0].e[j]) + bias[0].f[j];
    float gf = __bfloat162float(vg[1].e[j]) + bias[1].f[j];
    float go = __bfloat162float(vg[2].e[j]) + bias[2].f[j];
    float gc = __bfloat162float(vg[3].e[j]) + bias[3].f[j];
    float gs = __bfloat162float(vg[4].e[j]) + bias[4].f[j];
    float it = 1.f / (1.f + __expf(-gi));
    float ft = 1.f / (1.f + __expf(-gf));
    float ot = 1.f / (1.f + __expf(-go));
    float ch = tanhf(gc);
    float st = (1.f / (1.f + __expf(-gs))) * dv.f[j];
    float ct = ft * cp.f[j] + it * ch * st;
    oh.f[j] = ot * tanhf(ct);
    oc.f[j] = ct;
  }
  *(float4*)(out + ig)     = oh.v[0];
  *(float4*)(out + ig + 4) = oh.v[1];
  float* oc_p = out + (long)B_ROWS * HDIM + ig;
  *(float4*)(oc_p)     = oc.v[0];
  *(float4*)(oc_p + 4) = oc.v[1];
}

// ---------------------------------------------------------------------------
extern "C" void kernel_launch(void* const* d_in, const int* in_sizes, int n_in,
                              void* d_out, int out_size, void* d_ws, size_t ws_size,
                              hipStream_t stream) {
  const void* x      = d_in[0];
  const void* h_prev = d_in[1];
  const void* c_prev = d_in[2];
  const void* dw     = d_in[3];
  const void* Wx     = d_in[4];
  const void* bx     = d_in[5];
  const void* Uh     = d_in[6];
  const void* bh     = d_in[7];

  // one-time opt-in to 128 KiB dynamic LDS (host-side, graph-safe)
  static int lds_attr_done = 0;
  if (!lds_attr_done) {
    hipFuncSetAttribute((const void*)gemm_bt256,
                        hipFuncAttributeMaxDynamicSharedMemorySize, LDS_BYTES);
    lds_attr_done = 1;
  }

  // chunk count chosen from ws_size (host-constant -> graph-safe)
  const size_t wbf_bytes = (size_t)NDIM * KDIM * 2;  // 20 MiB
  int nc = 32;
  for (int c = 1; c <= 32; c <<= 1) {
    size_t need = 256 + wbf_bytes
                + (size_t)(B_ROWS / c) * KDIM * 2   // Abf chunk
                + (size_t)(B_ROWS / c) * NDIM * 2;  // G chunk
    if (need <= ws_size) { nc = c; break; }
  }
  const long rows = B_ROWS / nc;

  char* ws = (char*)d_ws;
  int* flag = (int*)ws;
  __hip_bfloat16* Wbf = (__hip_bfloat16*)(ws + 256);
  __hip_bfloat16* Abf = (__hip_bfloat16*)(ws + 256 + wbf_bytes);
  __hip_bfloat16* G   = (__hip_bfloat16*)(ws + 256 + wbf_bytes + (size_t)rows * KDIM * 2);

  detect_dtype<<<1, 256, 0, stream>>>((const unsigned short*)x, flag);

  pack_pair_f32<<<(int)(((long)NDIM * KDIM) / 2048), 256, 0, stream>>>(
      (const float*)Wx, (const float*)Uh, Wbf, flag, 0, (long)NDIM * KDIM);

  const bool use256 = (rows >= 4096);  // 256-tile grid >= 320 blocks

  for (int c = 0; c < nc; ++c) {
    long rbase = c * rows;
    pack_pair_f32<<<(int)rows, 256, 0, stream>>>(
        (const float*)x, (const float*)h_prev, Abf, flag, rbase, rows * KDIM);
    if (use256) {
      dim3 grid(NDIM / BN, (int)(rows / BM));
      gemm_bt256<<<grid, 512, LDS_BYTES, stream>>>(
          Abf, Wbf, x, h_prev, Wx, Uh, G, flag, (int)rbase);
    } else {
      dim3 grid(NDIM / 128, (int)(rows / 128));
      gemm_bt128<<<grid, 256, 0, stream>>>(
          Abf, Wbf, x, h_prev, Wx, Uh, G, flag, (int)rbase);
    }
    lstm_ep<<<(int)(rows * HDIM / 2048), 256, 0, stream>>>(
        G, c_prev, dw, bx, bh, (float*)d_out, flag, rbase, rows);
  }
}

// Round 3
// 681.570 us; speedup vs baseline: 1.0557x; 1.0557x over previous
//
#include <hip/hip_runtime.h>
#include <hip/hip_bf16.h>

#define B_ROWS 16384
#define KDIM   2048   // D + H
#define NDIM   5120   // 5*H
#define HDIM   1024

// ---- fused GEMM geometry: 256 x 320 tile (320 = 5 gates x 64 h) ----
#define BM 256
#define BN 320
#define BK 64
#define NKT (KDIM / BK)            // 32 K-tiles
#define A_BYTES (BM * BK * 2)      // 32768
#define W_BYTES (BN * BK * 2)      // 40960
#define BUFSZ   (A_BYTES + W_BYTES) // 73728
#define LDS_BYTES (2 * BUFSZ)      // 147456 dynamic LDS (opt-in)

typedef __attribute__((ext_vector_type(8))) short short8;
typedef __attribute__((ext_vector_type(4))) float f32x4;

__device__ __forceinline__ void async_cp16(const void* g, void* l) {
  __builtin_amdgcn_global_load_lds(
      (const __attribute__((address_space(1))) void*)g,
      (__attribute__((address_space(3))) void*)l,
      16, 0, 0);
}

// ---------------------------------------------------------------------------
// dtype probe: x is N(0,1). If stored bf16, no 16-bit word has exponent
// field >= 137 (|v| >= 2^10). If stored fp32, half the words are uniform
// mantissa noise -> ~46% exceed it. flag=1 -> fp32 inputs, flag=0 -> bf16.
// ---------------------------------------------------------------------------
__global__ void detect_dtype(const unsigned short* __restrict__ p, int* flag) {
  __shared__ int cnt;
  if (threadIdx.x == 0) cnt = 0;
  __syncthreads();
  int h = 0;
  for (int i = threadIdx.x; i < 2048; i += 256) {
    int e = (p[i] >> 7) & 0xFF;
    if (e >= 137) h++;
  }
  atomicAdd(&cnt, h);
  __syncthreads();
  if (threadIdx.x == 0) *flag = (cnt >= 4) ? 1 : 0;
}

// ---------------------------------------------------------------------------
// pack rows [rbase, rbase+rows) of fp32 (s0|s1) -> bf16 [rows,2048].
// No-op when inputs are already bf16 (flag==0).
// ---------------------------------------------------------------------------
__global__ void pack_pair_f32(const float* __restrict__ s0, const float* __restrict__ s1,
                              __hip_bfloat16* __restrict__ dst, const int* __restrict__ flag,
                              long rbase, long total) {
  if (*flag == 0) return;
  long idx = ((long)blockIdx.x * blockDim.x + threadIdx.x) * 8;
  if (idx >= total) return;
  int  k = (int)(idx & (KDIM - 1));
  long r = (idx >> 11) + rbase;
  const float* s = (k < 1024) ? (s0 + r * 1024 + k) : (s1 + r * 1024 + (k - 1024));
  float4 v0 = ((const float4*)s)[0];
  float4 v1 = ((const float4*)s)[1];
  union { short8 v; __hip_bfloat16 e[8]; } u;
  u.e[0] = __float2bfloat16(v0.x); u.e[1] = __float2bfloat16(v0.y);
  u.e[2] = __float2bfloat16(v0.z); u.e[3] = __float2bfloat16(v0.w);
  u.e[4] = __float2bfloat16(v1.x); u.e[5] = __float2bfloat16(v1.y);
  u.e[6] = __float2bfloat16(v1.z); u.e[7] = __float2bfloat16(v1.w);
  *(short8*)(dst + idx) = u.v;
}

// ---------------------------------------------------------------------------
// Fused GEMM + LSTM epilogue. 256x320 tile, BK=64, 2 LDS buffers,
// counted vmcnt(9) (depth-1 prefetch, never drained to 0 in main loop).
//
// W column permutation (applied at STAGING, not in memory): tile-local col
//   n = wn_grp*80 + g*16 + t   <-  W row  g*1024 + h0 + wn_grp*16 + t
// so wave wn's 5 N-frags are the 5 gates of h = h0 + wn*16 + (lane&15):
// the LSTM update is lane-local in acc[mi][g][r] - no cross-lane exchange,
// no G round-trip through HBM.
//
// LDS swizzle (both-sides, rule #21): 128-B rows, chunk sc holds data chunk
//   dc = sc ^ (row&7); staged via pre-swizzled global source (per-lane
//   constant (l&7)^(l>>3)); read with the same XOR (per-lane constant).
// ---------------------------------------------------------------------------
__global__ __launch_bounds__(512, 2) void gemm_fused(
    const __hip_bfloat16* __restrict__ Abf, const __hip_bfloat16* __restrict__ Wbf,
    const void* __restrict__ xr, const void* __restrict__ hr,
    const void* __restrict__ Wxr, const void* __restrict__ Uhr,
    const void* __restrict__ cpr, const void* __restrict__ dwr,
    const void* __restrict__ bxr, const void* __restrict__ bhr,
    float* __restrict__ out, const int* __restrict__ flag, int row_base) {
  extern __shared__ char lds[];

  const int tid = threadIdx.x;
  const int w   = tid >> 6;     // wave 0..7
  const int l   = tid & 63;

  const int m0l = blockIdx.y * BM;   // chunk-local row base
  const int h0  = blockIdx.x * 64;   // h-group base (16 groups)

  const int wm = w >> 2;   // 0..1
  const int wn = w & 3;    // 0..3

  const int fl = *flag;
  const int dc = (l & 7) ^ (l >> 3);   // staged data chunk (lane-const)

  // --- A staging: instr i covers rows m0l + (w + i*8)*8 + (l>>3) ---
  const __hip_bfloat16* srcA;
  long strA, dA;
  if (fl) {
    srcA = Abf + (long)(m0l + w * 8 + (l >> 3)) * KDIM + dc * 8;
    strA = KDIM; dA = 1024;
  } else {
    srcA = (const __hip_bfloat16*)xr
         + (long)(row_base + m0l + w * 8 + (l >> 3)) * 1024 + dc * 8;
    strA = 1024;
    dA = (const __hip_bfloat16*)hr - (const __hip_bfloat16*)xr;
  }

  // --- W staging: instr i covers tile rows j*8..j*8+8, j = w + i*8 ---
  const __hip_bfloat16* srcW[5];
  long dW;
  {
    const __hip_bfloat16* wbase;
    long strW;
    if (fl) { wbase = Wbf; strW = KDIM; dW = 1024; }
    else {
      wbase = (const __hip_bfloat16*)Wxr; strW = 1024;
      dW = (const __hip_bfloat16*)Uhr - (const __hip_bfloat16*)Wxr;
    }
#pragma unroll
    for (int i = 0; i < 5; ++i) {
      const int j  = w + i * 8;          // 0..39
      const int wg = j / 10;             // wn group 0..3
      const int q  = j % 10;             // 8-row range within group
      const int g  = q >> 1;             // gate 0..4
      const int hs = (q & 1) * 8 + (l >> 3);
      const long r_w = (long)g * 1024 + h0 + wg * 16 + hs;  // source W row
      srcW[i] = wbase + r_w * strW + dc * 8;
    }
  }

#define STAGE(T) do {                                                        \
    const int  b_  = (T) & 1;                                                \
    const int  k0_ = (T) * BK;                                               \
    const long koA_ = (k0_ < 1024) ? (long)k0_ : (dA + (k0_ - 1024));        \
    const long koW_ = (k0_ < 1024) ? (long)k0_ : (dW + (k0_ - 1024));        \
    char* lb_ = lds + b_ * BUFSZ;                                            \
    _Pragma("unroll")                                                        \
    for (int i_ = 0; i_ < 4; ++i_)                                           \
      async_cp16(srcA + koA_ + (long)i_ * 64 * strA,                         \
                 lb_ + (w + i_ * 8) * 1024 + l * 16);                        \
    _Pragma("unroll")                                                        \
    for (int i_ = 0; i_ < 5; ++i_)                                           \
      async_cp16(srcW[i_] + koW_,                                            \
                 lb_ + A_BYTES + (w + i_ * 8) * 1024 + l * 16);              \
  } while (0)

  f32x4 acc[8][5] = {};
  const int frow = l & 15;
  const int aoff0 = (wm * 128 + frow) * 128;          // A row byte base
  const int woff0 = A_BYTES + (wn * 80 + frow) * 128; // W row byte base

#define COMPUTE(T) do {                                                      \
    const char* ba_ = lds + ((T) & 1) * BUFSZ;                               \
    _Pragma("unroll")                                                        \
    for (int kk = 0; kk < 2; ++kk) {                                         \
      const int sc_ = ((kk * 4 + (l >> 4)) ^ (l & 7)) * 16;                  \
      short8 wf_[5], af_[8];                                                 \
      _Pragma("unroll")                                                      \
      for (int nj = 0; nj < 5; ++nj)                                         \
        wf_[nj] = *(const short8*)(ba_ + woff0 + nj * 2048 + sc_);           \
      _Pragma("unroll")                                                      \
      for (int mi = 0; mi < 8; ++mi)                                         \
        af_[mi] = *(const short8*)(ba_ + aoff0 + mi * 2048 + sc_);           \
      __builtin_amdgcn_s_setprio(1);                                         \
      _Pragma("unroll")                                                      \
      for (int mi = 0; mi < 8; ++mi)                                         \
        _Pragma("unroll")                                                    \
        for (int nj = 0; nj < 5; ++nj)                                       \
          acc[mi][nj] = __builtin_amdgcn_mfma_f32_16x16x32_bf16(             \
              af_[mi], wf_[nj], acc[mi][nj], 0, 0, 0);                       \
      __builtin_amdgcn_s_setprio(0);                                         \
    }                                                                        \
  } while (0)

  STAGE(0);

  // main loop: depth-1 prefetch, counted vmcnt(9) -- tile t+1 stays in flight
  for (int t = 0; t < NKT - 1; ++t) {
    __builtin_amdgcn_s_barrier();            // all waves done reading buf[(t+1)&1]
    __builtin_amdgcn_sched_barrier(0);
    STAGE(t + 1);
    asm volatile("s_waitcnt vmcnt(9)" ::: "memory");  // tile t landed
    __builtin_amdgcn_sched_barrier(0);
    __builtin_amdgcn_s_barrier();            // tile t visible to all waves
    __builtin_amdgcn_sched_barrier(0);
    COMPUTE(t);
  }
  // last tile: drain
  __builtin_amdgcn_s_barrier();
  asm volatile("s_waitcnt vmcnt(0)" ::: "memory");
  __builtin_amdgcn_sched_barrier(0);
  __builtin_amdgcn_s_barrier();
  __builtin_amdgcn_sched_barrier(0);
  COMPUTE(NKT - 1);

#undef STAGE
#undef COMPUTE

  // ---- fused LSTM epilogue: all 5 gates of h are lane-local ----
  // C layout (m89): col = lane&15 -> gate frag nj = gate g; row = (l>>4)*4 + r
  const int hh = h0 + wn * 16 + frow;     // global h index (0..1023)
  float bsum[5];
#pragma unroll
  for (int g = 0; g < 5; ++g) {
    if (fl) {
      bsum[g] = ((const float*)bxr)[g * 1024 + hh] + ((const float*)bhr)[g * 1024 + hh];
    } else {
      bsum[g] = __bfloat162float(((const __hip_bfloat16*)bxr)[g * 1024 + hh])
              + __bfloat162float(((const __hip_bfloat16*)bhr)[g * 1024 + hh]);
    }
  }
  const long orow0 = (long)row_base + m0l + wm * 128 + (l >> 4) * 4;
  float* outc = out + (long)B_ROWS * HDIM;
#pragma unroll
  for (int mi = 0; mi < 8; ++mi) {
#pragma unroll
    for (int r = 0; r < 4; ++r) {
      const long idx = (orow0 + mi * 16 + r) * HDIM + hh;
      float cp, dv;
      if (fl) {
        cp = ((const float*)cpr)[idx];
        dv = ((const float*)dwr)[idx];
      } else {
        cp = __bfloat162float(((const __hip_bfloat16*)cpr)[idx]);
        dv = __bfloat162float(((const __hip_bfloat16*)dwr)[idx]);
      }
      const float gi = acc[mi][0][r] + bsum[0];
      const float gf = acc[mi][1][r] + bsum[1];
      const float go = acc[mi][2][r] + bsum[2];
      const float gc = acc[mi][3][r] + bsum[3];
      const float gs = acc[mi][4][r] + bsum[4];
      const float it = 1.f / (1.f + __expf(-gi));
      const float ft = 1.f / (1.f + __expf(-gf));
      const float ot = 1.f / (1.f + __expf(-go));
      const float ch = tanhf(gc);
      const float st = (1.f / (1.f + __expf(-gs))) * dv;
      const float ct = ft * cp + it * ch * st;
      out[idx]  = ot * tanhf(ct);
      outc[idx] = ct;
    }
  }
}

// ---------------------------------------------------------------------------
extern "C" void kernel_launch(void* const* d_in, const int* in_sizes, int n_in,
                              void* d_out, int out_size, void* d_ws, size_t ws_size,
                              hipStream_t stream) {
  const void* x      = d_in[0];
  const void* h_prev = d_in[1];
  const void* c_prev = d_in[2];
  const void* dw     = d_in[3];
  const void* Wx     = d_in[4];
  const void* bx     = d_in[5];
  const void* Uh     = d_in[6];
  const void* bh     = d_in[7];

  // one-time opt-in to 144 KiB dynamic LDS (host-side, graph-safe)
  static int lds_attr_done = 0;
  if (!lds_attr_done) {
    hipFuncSetAttribute((const void*)gemm_fused,
                        hipFuncAttributeMaxDynamicSharedMemorySize, LDS_BYTES);
    lds_attr_done = 1;
  }

  // chunk count chosen from ws_size (host-constant -> graph-safe)
  const size_t wbf_bytes = (size_t)NDIM * KDIM * 2;  // 20 MiB
  int nc = 32;
  for (int c = 1; c <= 32; c <<= 1) {
    size_t need = 256 + wbf_bytes
                + (size_t)(B_ROWS / c) * KDIM * 2;   // Abf chunk
    if (need <= ws_size) { nc = c; break; }
  }
  const long rows = B_ROWS / nc;

  char* ws = (char*)d_ws;
  int* flag = (int*)ws;
  __hip_bfloat16* Wbf = (__hip_bfloat16*)(ws + 256);
  __hip_bfloat16* Abf = (__hip_bfloat16*)(ws + 256 + wbf_bytes);

  detect_dtype<<<1, 256, 0, stream>>>((const unsigned short*)x, flag);

  pack_pair_f32<<<(int)(((long)NDIM * KDIM) / 2048), 256, 0, stream>>>(
      (const float*)Wx, (const float*)Uh, Wbf, flag, 0, (long)NDIM * KDIM);

  for (int c = 0; c < nc; ++c) {
    long rbase = c * rows;
    pack_pair_f32<<<(int)rows, 256, 0, stream>>>(
        (const float*)x, (const float*)h_prev, Abf, flag, rbase, rows * KDIM);
    dim3 grid(NDIM / BN, (int)(rows / BM));
    gemm_fused<<<grid, 512, LDS_BYTES, stream>>>(
        Abf, Wbf, x, h_prev, Wx, Uh, c_prev, dw, bx, bh,
        (float*)d_out, flag, (int)rbase);
  }
}